// Round 16
// baseline (180.005 us; speedup 1.0000x reference)
//
#include <hip/hip_runtime.h>

// Shapes: N=8, C=512, T=8, H=32, W=32, HW=1024, THW=8192, CI=256, CA=128
// All tensor I/O is FLOAT32.
//
// Factorization (phi(audio) constant over h,w):
//   at[n,t,c]   = relu(audio[n,t,:]·alignW[c,:] + alignB[c])          (output 2)
//   phi[n,i,t]  = Wph[i,:]·at[n,t,:] + bph[i]
//   M[n,c,t]    = sum_i Wth[i,c]·phi[n,i,t];  const[n,t] = sum_i bth[i]·phi[n,i,t]
//   Xsum[n,t,c] = sum_hw x[n,c,t,hw]
//   G[n,t,o]    = Wg[o,:]·Xsum[n,t,:] + 1024·bg[o];  GW[n,t,c] = Wz[c,:]·G[n,t,:]
//   f[n,s,t]    = x[n,:,s]·M[n,:,t] + const[n,t]
//   W_y[n,s,c]  = (1/8192)·sum_t f[n,s,t]·GW[n,t,c] + bz[c]
//   BN stats folded once in k_bn -> gw2/pack0 tables
//   z = LN_c(0.5·BN(W_y) + 0.5·x)                                    (output 1)
//
// R16: xsum and fsmall — the two independent cold readers of x — share ONE
// launch window (k_B) instead of running in back-to-back kernels. k_A =
// audio chain alone. Lessons: R5 (x = only VMEM stream), R6 (no in-graph
// memset), R8/R9 (2 blocks/CU, launch_bounds(512,4)), R10 (no cooperative
// launch), R11 (coalesce weight loads), R14 (no in-loop xsum fusion: spills).

typedef float __attribute__((ext_vector_type(2))) f32x2;

__device__ __forceinline__ float hsum4(float4 v) { return (v.x + v.y) + (v.z + v.w); }
__device__ __forceinline__ void fma4v(float4& a, float4 w, float4 x) {
    a.x = fmaf(w.x, x.x, a.x); a.y = fmaf(w.y, x.y, a.y);
    a.z = fmaf(w.z, x.z, a.z); a.w = fmaf(w.w, x.w, a.w);
}

// ---------------- k_A: audio chain only (64 blocks) ----------------
__global__ __launch_bounds__(256) void k_A(
    const float* __restrict__ audio,
    const float* __restrict__ alignW, const float* __restrict__ alignB,
    const float* __restrict__ Wph, const float* __restrict__ bph,
    const float* __restrict__ Wth, const float* __restrict__ bth,
    float* __restrict__ outA, float* __restrict__ constT, float* __restrict__ M)
{
    int b = blockIdx.x; int tid = threadIdx.x;
    int n = b >> 3; int t = b & 7;
    __shared__ float al[128];
    __shared__ float atl[512];
    __shared__ float phil[256];
    __shared__ float red[256];
    if (tid < 32)
        reinterpret_cast<float4*>(al)[tid] =
            reinterpret_cast<const float4*>(audio + (n * 8 + t) * 128)[tid];
    __syncthreads();
    {   // at[c] for c = tid, tid+256 : float4 row loads, 4 indep accumulators
        const float4* W0 = reinterpret_cast<const float4*>(alignW + (size_t)tid * 128);
        const float4* W1 = reinterpret_cast<const float4*>(alignW + (size_t)(tid + 256) * 128);
        const float4* A4 = reinterpret_cast<const float4*>(al);
        float4 s00 = {0,0,0,0}, s01 = {0,0,0,0}, s10 = {0,0,0,0}, s11 = {0,0,0,0};
        #pragma unroll
        for (int k = 0; k < 32; k += 2) {
            float4 a0 = A4[k], a1 = A4[k + 1];
            fma4v(s00, W0[k], a0); fma4v(s01, W0[k + 1], a1);
            fma4v(s10, W1[k], a0); fma4v(s11, W1[k + 1], a1);
        }
        float v0 = fmaxf(alignB[tid] + hsum4(s00) + hsum4(s01), 0.f);
        float v1 = fmaxf(alignB[tid + 256] + hsum4(s10) + hsum4(s11), 0.f);
        atl[tid] = v0;       outA[(n * 8 + t) * 512 + tid] = v0;
        atl[tid + 256] = v1; outA[(n * 8 + t) * 512 + tid + 256] = v1;
    }
    __syncthreads();
    {   // phi[i], i = tid : 128 float4 row loads, 4 accumulators
        const float4* Wp = reinterpret_cast<const float4*>(Wph + (size_t)tid * 512);
        const float4* At = reinterpret_cast<const float4*>(atl);
        float4 s0 = {0,0,0,0}, s1 = {0,0,0,0}, s2 = {0,0,0,0}, s3 = {0,0,0,0};
        #pragma unroll 4
        for (int k = 0; k < 128; k += 4) {
            fma4v(s0, Wp[k], At[k]);         fma4v(s1, Wp[k + 1], At[k + 1]);
            fma4v(s2, Wp[k + 2], At[k + 2]); fma4v(s3, Wp[k + 3], At[k + 3]);
        }
        float acc = bph[tid] + (hsum4(s0) + hsum4(s1)) + (hsum4(s2) + hsum4(s3));
        phil[tid] = acc;
        red[tid] = acc * bth[tid];
    }
    __syncthreads();
    for (int sr = 128; sr > 0; sr >>= 1) {      // const[n,t]
        if (tid < sr) red[tid] += red[tid + sr];
        __syncthreads();
    }
    if (tid == 0) constT[n * 8 + t] = red[0];
    {   // M[c] for c = tid, tid+256 : coalesced over i, 8 loads in flight
        float a0 = 0, a1 = 0, a2 = 0, a3 = 0, c0 = 0, c1 = 0, c2 = 0, c3 = 0;
        #pragma unroll 2
        for (int i = 0; i < 256; i += 4) {
            float p0 = phil[i], p1 = phil[i + 1], p2 = phil[i + 2], p3 = phil[i + 3];
            const float* W = Wth + (size_t)i * 512 + tid;
            a0 = fmaf(W[0], p0, a0);    a1 = fmaf(W[512], p1, a1);
            a2 = fmaf(W[1024], p2, a2); a3 = fmaf(W[1536], p3, a3);
            const float* W2 = W + 256;
            c0 = fmaf(W2[0], p0, c0);    c1 = fmaf(W2[512], p1, c1);
            c2 = fmaf(W2[1024], p2, c2); c3 = fmaf(W2[1536], p3, c3);
        }
        M[n * 4096 + tid * 8 + t] = (a0 + a1) + (a2 + a3);
        M[n * 4096 + (tid + 256) * 8 + t] = (c0 + c1) + (c2 + c3);
    }
}

// ---------------- k_B: fsmall (blocks 0..511) ∥ xsum (blocks 512..4607) ----------------
// Both consume the same cold x stream in one launch window.
__global__ __launch_bounds__(512, 4) void k_B(
    const float* __restrict__ x, const float* __restrict__ M,
    const float* __restrict__ constT, float* __restrict__ fs,
    float* __restrict__ Part, float* __restrict__ xsT)
{
    int b = blockIdx.x; int tid = threadIdx.x;
    int lane = tid & 63; int wv = tid >> 6;
    __shared__ float Ml[512][8];                // fsmall: 16 KB
    __shared__ float ldsT[8][8][130];           // fsmall: 33.3 KB
    __shared__ float partm[2][44];
    if (b >= 512) {
        // ---- xsum: 8 rows of 1024, one wave each; write transposed [n][t][c] ----
        int row = (b - 512) * 8 + wv;
        const float4* p = reinterpret_cast<const float4*>(x + (size_t)row * 1024);
        float s = 0.f;
        #pragma unroll
        for (int k = 0; k < 4; ++k) {
            float4 v = p[lane + 64 * k];
            s += v.x + v.y + v.z + v.w;
        }
        for (int off = 32; off > 0; off >>= 1) s += __shfl_down(s, off);
        if (lane == 0) {
            int n = row >> 12, c = (row >> 3) & 511, t = row & 7;
            xsT[((size_t)n * 8 + t) * 512 + c] = s;
        }
        return;
    }
    // ---- fsmall for block b (verbatim R13/R15 logic) ----
    int n = b >> 6; int s0i = (b & 63) << 7;
    {
        const float4* src = reinterpret_cast<const float4*>(M + n * 4096);
        float4* dst = reinterpret_cast<float4*>(&Ml[0][0]);
        for (int i = tid; i < 1024; i += 512) dst[i] = src[i];
    }
    __syncthreads();
    const float* xb = x + (size_t)n * 4194304 + s0i + lane * 2;
    float2 p2[8];
    #pragma unroll
    for (int k = 0; k < 8; ++k) p2[k] = make_float2(0.f, 0.f);
    #pragma unroll 16
    for (int j = 0; j < 64; ++j) {
        int c = wv * 64 + j;
        float2 xv = *reinterpret_cast<const float2*>(xb + (size_t)c * 8192);
        float4 m0 = *reinterpret_cast<const float4*>(&Ml[c][0]);
        float4 m1 = *reinterpret_cast<const float4*>(&Ml[c][4]);
        p2[0].x = fmaf(xv.x, m0.x, p2[0].x); p2[0].y = fmaf(xv.y, m0.x, p2[0].y);
        p2[1].x = fmaf(xv.x, m0.y, p2[1].x); p2[1].y = fmaf(xv.y, m0.y, p2[1].y);
        p2[2].x = fmaf(xv.x, m0.z, p2[2].x); p2[2].y = fmaf(xv.y, m0.z, p2[2].y);
        p2[3].x = fmaf(xv.x, m0.w, p2[3].x); p2[3].y = fmaf(xv.y, m0.w, p2[3].y);
        p2[4].x = fmaf(xv.x, m1.x, p2[4].x); p2[4].y = fmaf(xv.y, m1.x, p2[4].y);
        p2[5].x = fmaf(xv.x, m1.y, p2[5].x); p2[5].y = fmaf(xv.y, m1.y, p2[5].y);
        p2[6].x = fmaf(xv.x, m1.z, p2[6].x); p2[6].y = fmaf(xv.y, m1.z, p2[6].y);
        p2[7].x = fmaf(xv.x, m1.w, p2[7].x); p2[7].y = fmaf(xv.y, m1.w, p2[7].y);
    }
    #pragma unroll
    for (int k = 0; k < 8; ++k)
        *reinterpret_cast<float2*>(&ldsT[wv][k][lane * 2]) = p2[k];
    __syncthreads();
    if (tid < 128) {
        int tok = tid; int wq = tid >> 6;
        const float* ct = constT + n * 8;
        float q[8];
        #pragma unroll
        for (int k = 0; k < 8; ++k) {
            float v = ct[k];
            #pragma unroll
            for (int g = 0; g < 8; ++g) v += ldsT[g][k][tok];
            q[k] = v;
        }
        float4* op = reinterpret_cast<float4*>(fs + ((size_t)n * 8192 + s0i + tok) * 8);
        op[0] = make_float4(q[0], q[1], q[2], q[3]);
        op[1] = make_float4(q[4], q[5], q[6], q[7]);
        float mom[44];
        {
            int idx = 8;
            for (int t1 = 0; t1 < 8; ++t1) {
                mom[t1] = q[t1];
                for (int t2 = t1; t2 < 8; ++t2) { mom[idx] = q[t1] * q[t2]; ++idx; }
            }
        }
        for (int k = 0; k < 44; ++k)
            for (int off = 32; off > 0; off >>= 1) mom[k] += __shfl_down(mom[k], off);
        if ((tid & 63) == 0)
            for (int k = 0; k < 44; ++k) partm[wq][k] = mom[k];
    }
    __syncthreads();
    if (tid < 44) Part[b * 44 + tid] = partm[0][tid] + partm[1][tid];
}

// ---------------- k_GGW: Xsum -> G -> GW (64 blocks) ----------------
__global__ __launch_bounds__(512) void k_GGW(
    const float* __restrict__ xsT, const float* __restrict__ Wg,
    const float* __restrict__ bg, const float* __restrict__ Wz,
    float* __restrict__ GW)
{
    int b2 = blockIdx.x; int n = b2 >> 3; int t = b2 & 7; int tid = threadIdx.x;
    __shared__ float xsl[512];
    __shared__ float gl[256];
    xsl[tid] = xsT[((size_t)n * 8 + t) * 512 + tid];   // coalesced
    __syncthreads();
    if (tid < 256) {                            // G[o] : 128 f4 loads
        const float4* Wr = reinterpret_cast<const float4*>(Wg + (size_t)tid * 512);
        const float4* X4 = reinterpret_cast<const float4*>(xsl);
        float4 s0 = {0,0,0,0}, s1 = {0,0,0,0}, s2 = {0,0,0,0}, s3 = {0,0,0,0};
        #pragma unroll 4
        for (int k = 0; k < 128; k += 4) {
            fma4v(s0, Wr[k], X4[k]);         fma4v(s1, Wr[k + 1], X4[k + 1]);
            fma4v(s2, Wr[k + 2], X4[k + 2]); fma4v(s3, Wr[k + 3], X4[k + 3]);
        }
        gl[tid] = 1024.f * bg[tid] + (hsum4(s0) + hsum4(s1)) + (hsum4(s2) + hsum4(s3));
    }
    __syncthreads();
    {                                           // GW[c] : 64 f4 loads
        const float4* Wr = reinterpret_cast<const float4*>(Wz + (size_t)tid * 256);
        const float4* G4 = reinterpret_cast<const float4*>(gl);
        float4 s0 = {0,0,0,0}, s1 = {0,0,0,0}, s2 = {0,0,0,0}, s3 = {0,0,0,0};
        #pragma unroll 4
        for (int k = 0; k < 64; k += 4) {
            fma4v(s0, Wr[k], G4[k]);         fma4v(s1, Wr[k + 1], G4[k + 1]);
            fma4v(s2, Wr[k + 2], G4[k + 2]); fma4v(s3, Wr[k + 3], G4[k + 3]);
        }
        GW[((size_t)n * 8 + t) * 512 + tid] =
            (hsum4(s0) + hsum4(s1)) + (hsum4(s2) + hsum4(s3));
    }
}

// ---------------- k_bn: fold Part -> BN stats -> gw2/pack0 tables (8 blocks) ----------------
__global__ __launch_bounds__(512) void k_bn(
    const float* __restrict__ Part, const float* __restrict__ GW,
    const float* __restrict__ bz, const float* __restrict__ bng, const float* __restrict__ bnb,
    const float* __restrict__ lng, const float* __restrict__ lnb,
    float* __restrict__ pack0, float* __restrict__ gw2)
{
    int n0 = blockIdx.x; int c = threadIdx.x;
    __shared__ float Fl[64];
    __shared__ float S2l[512];
    if (c < 352) {                              // 8 n x 44 moments; 64 blocks per n
        int n = c / 44, k = c % 44;
        float v = 0.f;
        for (int i = 0; i < 64; ++i) v += Part[(n * 64 + i) * 44 + k];
        if (k < 8) Fl[n * 8 + k] = v;
        else {
            int kk = k - 8; int t1 = 0;
            while (kk >= 8 - t1) { kk -= 8 - t1; ++t1; }
            int t2 = t1 + kk;
            S2l[n * 64 + t1 * 8 + t2] = v;
            S2l[n * 64 + t2 * 8 + t1] = v;
        }
    }
    __syncthreads();
    const float r = 1.f / 8192.f;
    float meanu = 0.f, e2 = 0.f;
    float gmine[8];
    for (int n2 = 0; n2 < 8; ++n2) {
        float g[8];
        #pragma unroll
        for (int t = 0; t < 8; ++t) g[t] = GW[(n2 * 8 + t) * 512 + c];
        if (n2 == n0) {
            #pragma unroll
            for (int t = 0; t < 8; ++t) gmine[t] = g[t];
        }
        #pragma unroll
        for (int t = 0; t < 8; ++t) meanu += Fl[n2 * 8 + t] * g[t];
        for (int t1 = 0; t1 < 8; ++t1)
            #pragma unroll
            for (int t2 = 0; t2 < 8; ++t2) e2 += S2l[n2 * 64 + t1 * 8 + t2] * g[t1] * g[t2];
    }
    const float invCnt = 1.f / 65536.f;
    meanu *= r * invCnt;
    e2 *= r * r * invCnt;
    float var = fmaxf(e2 - meanu * meanu, 0.f);
    float bzv = bz[c];
    float sc = bng[c] * rsqrtf(var + 1e-5f);
    float sh = bnb[c] - (meanu + bzv) * sc;
    if (n0 == 0) {
        float4 pk;
        pk.x = 0.5f * (bzv * sc + sh);          // constant part of 0.5*BN(W_y)
        pk.y = lng[c];
        pk.z = lnb[c];
        pk.w = 0.f;
        *reinterpret_cast<float4*>(pack0 + c * 4) = pk;
    }
    float scale = 0.5f * r * sc;
    #pragma unroll
    for (int t = 0; t < 8; ++t)
        gw2[((size_t)n0 * 512 + c) * 8 + t] = gmine[t] * scale;
}

// ---------------- k_final: load tables + W_y reconstruct + blend + LayerNorm ----------------
__global__ __launch_bounds__(512, 4) void k_final(
    const float* __restrict__ x, const float* __restrict__ fs,
    const float* __restrict__ pack0, const float* __restrict__ gw2,
    float* __restrict__ outZ)
{
    int b = blockIdx.x; int n = b >> 6; int s0 = (b & 63) << 7;
    int tid = threadIdx.x; int lane = tid & 63; int wv = tid >> 6;
    __shared__ float GWl[512][8];               // 16 KB gw2[n] slice
    __shared__ float4 PKl[512];                 // 8 KB {sh2, lng, lnb, 0}
    __shared__ float redS[2][8][130];           // 8.3 KB
    {
        const float4* src = reinterpret_cast<const float4*>(gw2 + (size_t)n * 4096);
        float4* dst = reinterpret_cast<float4*>(&GWl[0][0]);
        for (int i = tid; i < 1024; i += 512) dst[i] = src[i];
        PKl[tid] = reinterpret_cast<const float4*>(pack0)[tid];
    }
    __syncthreads();
    float4 fA0, fB0, fA1, fB1;
    {
        const float4* fp = reinterpret_cast<const float4*>(fs + ((size_t)n * 8192 + s0 + lane * 2) * 8);
        fA0 = fp[0]; fB0 = fp[1]; fA1 = fp[2]; fB1 = fp[3];
    }
    const size_t xbase = (size_t)n * 4194304 + s0 + lane * 2;
    float2 s1 = make_float2(0.f, 0.f), sq = make_float2(0.f, 0.f);
    #pragma unroll 16
    for (int j = 0; j < 64; ++j) {
        int c = wv * 64 + j;
        float2 xv = *reinterpret_cast<const float2*>(&x[xbase + (size_t)c * 8192]);
        float4 g0 = *reinterpret_cast<const float4*>(&GWl[c][0]);
        float4 g1 = *reinterpret_cast<const float4*>(&GWl[c][4]);
        float pk0 = PKl[c].x;
        float z0 = pk0 + 0.5f * xv.x
            + fA0.x * g0.x + fA0.y * g0.y + fA0.z * g0.z + fA0.w * g0.w
            + fB0.x * g1.x + fB0.y * g1.y + fB0.z * g1.z + fB0.w * g1.w;
        float z1 = pk0 + 0.5f * xv.y
            + fA1.x * g0.x + fA1.y * g0.y + fA1.z * g0.z + fA1.w * g0.w
            + fB1.x * g1.x + fB1.y * g1.y + fB1.z * g1.z + fB1.w * g1.w;
        s1.x += z0; sq.x += z0 * z0;
        s1.y += z1; sq.y += z1 * z1;
    }
    *reinterpret_cast<float2*>(&redS[0][wv][lane * 2]) = s1;
    *reinterpret_cast<float2*>(&redS[1][wv][lane * 2]) = sq;
    __syncthreads();
    float mean0, rstd0, mean1, rstd1;
    {
        int t0 = lane * 2, t1 = lane * 2 + 1;
        float a0 = 0.f, q0 = 0.f, a1 = 0.f, q1 = 0.f;
        #pragma unroll
        for (int g = 0; g < 8; ++g) {
            a0 += redS[0][g][t0]; q0 += redS[1][g][t0];
            a1 += redS[0][g][t1]; q1 += redS[1][g][t1];
        }
        mean0 = a0 * (1.f / 512.f);
        rstd0 = rsqrtf(fmaxf(q0 * (1.f / 512.f) - mean0 * mean0, 0.f) + 1e-5f);
        mean1 = a1 * (1.f / 512.f);
        rstd1 = rsqrtf(fmaxf(q1 * (1.f / 512.f) - mean1 * mean1, 0.f) + 1e-5f);
    }
    #pragma unroll 16
    for (int j = 0; j < 64; ++j) {
        int c = wv * 64 + j;
        float2 xv = *reinterpret_cast<const float2*>(&x[xbase + (size_t)c * 8192]);
        float4 g0 = *reinterpret_cast<const float4*>(&GWl[c][0]);
        float4 g1 = *reinterpret_cast<const float4*>(&GWl[c][4]);
        float4 pk = PKl[c];
        float z0 = pk.x + 0.5f * xv.x
            + fA0.x * g0.x + fA0.y * g0.y + fA0.z * g0.z + fA0.w * g0.w
            + fB0.x * g1.x + fB0.y * g1.y + fB0.z * g1.z + fB0.w * g1.w;
        float z1 = pk.x + 0.5f * xv.y
            + fA1.x * g0.x + fA1.y * g0.y + fA1.z * g0.z + fA1.w * g0.w
            + fB1.x * g1.x + fB1.y * g1.y + fB1.z * g1.z + fB1.w * g1.w;
        f32x2 o;
        o.x = (z0 - mean0) * rstd0 * pk.y + pk.z;
        o.y = (z1 - mean1) * rstd1 * pk.y + pk.z;
        __builtin_nontemporal_store(o, reinterpret_cast<f32x2*>(&outZ[xbase + (size_t)c * 8192]));
    }
}

extern "C" void kernel_launch(void* const* d_in, const int* in_sizes, int n_in,
                              void* d_out, int out_size, void* d_ws, size_t ws_size,
                              hipStream_t stream)
{
    const float* x      = (const float*)d_in[0];
    const float* audio  = (const float*)d_in[1];
    const float* alignW = (const float*)d_in[2];
    const float* alignB = (const float*)d_in[3];
    const float* Wg     = (const float*)d_in[4];
    const float* bg     = (const float*)d_in[5];
    const float* Wth    = (const float*)d_in[6];
    const float* bth    = (const float*)d_in[7];
    const float* Wph    = (const float*)d_in[8];
    const float* bph    = (const float*)d_in[9];
    const float* Wz     = (const float*)d_in[10];
    const float* bz     = (const float*)d_in[11];
    const float* bng    = (const float*)d_in[12];
    const float* bnb    = (const float*)d_in[13];
    const float* lng    = (const float*)d_in[14];
    const float* lnb    = (const float*)d_in[15];
    float* outZ = (float*)d_out;
    float* outA = outZ + 33554432;  // z (N,C,T,H,W) then audio_temp (N,T,C)

    uintptr_t pa = ((uintptr_t)d_ws + 255) & ~(uintptr_t)255;
    float* w = (float*)pa;

    float* constT = w;              // 64
    float* M      = w + 64;         // 32768  [n][c][t]
    float* XS     = w + 32832;      // 32768  transposed [n][t][c]
    float* GW     = w + 65600;      // 32768  [n][t][c]
    float* Part   = w + 98368;      // 22528  [512 blocks][44] moment partials
    float* pack0  = w + 120896;     // 2048   float4 per c: {sh2, ln_g, ln_b, 0}
    float* gw2    = w + 122944;     // 32768  [n][c][t] folded with 0.5*r*bn_scale
    float* fsm    = w + 155712;     // 524288 [n][s][t]
    // every buffer fully written before read each call -> no memset needed

    k_A<<<64, 256, 0, stream>>>(audio, alignW, alignB, Wph, bph, Wth, bth,
                                outA, constT, M);
    k_B<<<4608, 512, 0, stream>>>(x, M, constT, fsm, Part, XS);  // fsmall ∥ xsum
    k_GGW<<<64, 512, 0, stream>>>(XS, Wg, bg, Wz, GW);
    k_bn<<<8, 512, 0, stream>>>(Part, GW, bz, bng, bnb, lng, lnb, pack0, gw2);
    k_final<<<512, 512, 0, stream>>>(x, fsm, pack0, gw2, outZ);
}

// Round 17
// 170.195 us; speedup vs baseline: 1.0576x; 1.0576x over previous
//
#include <hip/hip_runtime.h>

// Shapes: N=8, C=512, T=8, H=32, W=32, HW=1024, THW=8192, CI=256, CA=128
// All tensor I/O is FLOAT32.
//
// Factorization (phi(audio) constant over h,w):
//   at[n,t,c]   = relu(audio[n,t,:]·alignW[c,:] + alignB[c])          (output 2)
//   phi[n,i,t]  = Wph[i,:]·at[n,t,:] + bph[i]
//   M[n,c,t]    = sum_i Wth[i,c]·phi[n,i,t];  const[n,t] = sum_i bth[i]·phi[n,i,t]
//   Xsum[n,t,c] = sum_hw x[n,c,t,hw]          (stored transposed for stage2)
//   G[n,t,o]    = Wg[o,:]·Xsum[n,t,:] + 1024·bg[o];  GW[n,t,c] = Wz[c,:]·G[n,t,:]
//   f[n,s,t]    = x[n,:,s]·M[n,:,t] + const[n,t]
//   W_y[n,s,c]  = (1/8192)·sum_t f[n,s,t]·GW[n,t,c] + bz[c]
//   BN stats from per-block moment partials Part[b][44]
//   z = LN_c(0.5·BN(W_y) + 0.5·x)                                    (output 1)
//
// R17 = exact revert to R13 (best measured: 170.8 us). R14 (xsum fused in
// loop: spills, 242), R15 (separate bn: 172), R16 (xsum moved beside
// fsmall: 180) all bracketed R13 from three directions -> R13's schedule
// {audio ∥ xsum} -> {fsmall ∥ G/GW} -> {final + redundant BN fold} is the
// practical floor of this 4-launch pipeline.

typedef float __attribute__((ext_vector_type(2))) f32x2;

__device__ __forceinline__ float hsum4(float4 v) { return (v.x + v.y) + (v.z + v.w); }
__device__ __forceinline__ void fma4v(float4& a, float4 w, float4 x) {
    a.x = fmaf(w.x, x.x, a.x); a.y = fmaf(w.y, x.y, a.y);
    a.z = fmaf(w.z, x.z, a.z); a.w = fmaf(w.w, x.w, a.w);
}

// ---------------- stage1: audio chain (blocks 0..63) ∥ xsum (blocks 64..8255) ----------------
__global__ __launch_bounds__(256) void k_stage1(
    const float* __restrict__ x, const float* __restrict__ audio,
    const float* __restrict__ alignW, const float* __restrict__ alignB,
    const float* __restrict__ Wph, const float* __restrict__ bph,
    const float* __restrict__ Wth, const float* __restrict__ bth,
    float* __restrict__ outA, float* __restrict__ constT, float* __restrict__ M,
    float* __restrict__ xsT)
{
    int b = blockIdx.x; int tid = threadIdx.x;
    __shared__ float al[128];
    __shared__ float atl[512];
    __shared__ float phil[256];
    __shared__ float red[256];
    if (b >= 64) {
        // ---- xsum: 4 rows of 1024, one wave each; write transposed [n][t][c] ----
        int row = (b - 64) * 4 + (tid >> 6);
        int lane = tid & 63;
        const float4* p = reinterpret_cast<const float4*>(x + (size_t)row * 1024);
        float s = 0.f;
        #pragma unroll
        for (int k = 0; k < 4; ++k) {
            float4 v = p[lane + 64 * k];
            s += v.x + v.y + v.z + v.w;
        }
        for (int off = 32; off > 0; off >>= 1) s += __shfl_down(s, off);
        if (lane == 0) {
            int n = row >> 12, c = (row >> 3) & 511, t = row & 7;
            xsT[((size_t)n * 8 + t) * 512 + c] = s;
        }
        return;
    }
    // ---- audio chain for (n,t) ----
    int n = b >> 3; int t = b & 7;
    if (tid < 32)
        reinterpret_cast<float4*>(al)[tid] =
            reinterpret_cast<const float4*>(audio + (n * 8 + t) * 128)[tid];
    __syncthreads();
    {   // at[c] for c = tid, tid+256 : float4 row loads, 4 indep accumulators
        const float4* W0 = reinterpret_cast<const float4*>(alignW + (size_t)tid * 128);
        const float4* W1 = reinterpret_cast<const float4*>(alignW + (size_t)(tid + 256) * 128);
        const float4* A4 = reinterpret_cast<const float4*>(al);
        float4 s00 = {0,0,0,0}, s01 = {0,0,0,0}, s10 = {0,0,0,0}, s11 = {0,0,0,0};
        #pragma unroll
        for (int k = 0; k < 32; k += 2) {
            float4 a0 = A4[k], a1 = A4[k + 1];
            fma4v(s00, W0[k], a0); fma4v(s01, W0[k + 1], a1);
            fma4v(s10, W1[k], a0); fma4v(s11, W1[k + 1], a1);
        }
        float v0 = fmaxf(alignB[tid] + hsum4(s00) + hsum4(s01), 0.f);
        float v1 = fmaxf(alignB[tid + 256] + hsum4(s10) + hsum4(s11), 0.f);
        atl[tid] = v0;       outA[(n * 8 + t) * 512 + tid] = v0;
        atl[tid + 256] = v1; outA[(n * 8 + t) * 512 + tid + 256] = v1;
    }
    __syncthreads();
    {   // phi[i], i = tid : 128 float4 row loads, 4 accumulators
        const float4* Wp = reinterpret_cast<const float4*>(Wph + (size_t)tid * 512);
        const float4* At = reinterpret_cast<const float4*>(atl);
        float4 s0 = {0,0,0,0}, s1 = {0,0,0,0}, s2 = {0,0,0,0}, s3 = {0,0,0,0};
        #pragma unroll 4
        for (int k = 0; k < 128; k += 4) {
            fma4v(s0, Wp[k], At[k]);         fma4v(s1, Wp[k + 1], At[k + 1]);
            fma4v(s2, Wp[k + 2], At[k + 2]); fma4v(s3, Wp[k + 3], At[k + 3]);
        }
        float acc = bph[tid] + (hsum4(s0) + hsum4(s1)) + (hsum4(s2) + hsum4(s3));
        phil[tid] = acc;
        red[tid] = acc * bth[tid];
    }
    __syncthreads();
    for (int sr = 128; sr > 0; sr >>= 1) {      // const[n,t]
        if (tid < sr) red[tid] += red[tid + sr];
        __syncthreads();
    }
    if (tid == 0) constT[n * 8 + t] = red[0];
    {   // M[c] for c = tid, tid+256 : coalesced over i, 8 loads in flight
        float a0 = 0, a1 = 0, a2 = 0, a3 = 0, c0 = 0, c1 = 0, c2 = 0, c3 = 0;
        #pragma unroll 2
        for (int i = 0; i < 256; i += 4) {
            float p0 = phil[i], p1 = phil[i + 1], p2 = phil[i + 2], p3 = phil[i + 3];
            const float* W = Wth + (size_t)i * 512 + tid;
            a0 = fmaf(W[0], p0, a0);    a1 = fmaf(W[512], p1, a1);
            a2 = fmaf(W[1024], p2, a2); a3 = fmaf(W[1536], p3, a3);
            const float* W2 = W + 256;
            c0 = fmaf(W2[0], p0, c0);    c1 = fmaf(W2[512], p1, c1);
            c2 = fmaf(W2[1024], p2, c2); c3 = fmaf(W2[1536], p3, c3);
        }
        M[n * 4096 + tid * 8 + t] = (a0 + a1) + (a2 + a3);
        M[n * 4096 + (tid + 256) * 8 + t] = (c0 + c1) + (c2 + c3);
    }
}

// ---------------- stage2: fsmall (blocks 0..511) ∥ G/GW (blocks 512..575) ----------------
__global__ __launch_bounds__(512, 4) void k_stage2(
    const float* __restrict__ x, const float* __restrict__ M,
    const float* __restrict__ constT, const float* __restrict__ xsT,
    const float* __restrict__ Wg, const float* __restrict__ bg,
    const float* __restrict__ Wz,
    float* __restrict__ fs, float* __restrict__ Part, float* __restrict__ GW)
{
    int b = blockIdx.x; int tid = threadIdx.x;
    __shared__ float Ml[512][8];                // fsmall: 16 KB
    __shared__ float ldsT[8][8][130];           // fsmall: 33.3 KB
    __shared__ float partm[2][44];
    __shared__ float xsl[512];                  // G/GW: 2 KB
    __shared__ float gl[256];                   // G/GW: 1 KB
    if (b >= 512) {
        // ---- G then GW for (n,t) ----
        int b2 = b - 512; int n = b2 >> 3; int t = b2 & 7;
        xsl[tid] = xsT[((size_t)n * 8 + t) * 512 + tid];   // coalesced
        __syncthreads();
        if (tid < 256) {                        // G[o], o = tid : 128 f4 loads
            const float4* Wr = reinterpret_cast<const float4*>(Wg + (size_t)tid * 512);
            const float4* X4 = reinterpret_cast<const float4*>(xsl);
            float4 s0 = {0,0,0,0}, s1 = {0,0,0,0}, s2 = {0,0,0,0}, s3 = {0,0,0,0};
            #pragma unroll 4
            for (int k = 0; k < 128; k += 4) {
                fma4v(s0, Wr[k], X4[k]);         fma4v(s1, Wr[k + 1], X4[k + 1]);
                fma4v(s2, Wr[k + 2], X4[k + 2]); fma4v(s3, Wr[k + 3], X4[k + 3]);
            }
            gl[tid] = 1024.f * bg[tid] + (hsum4(s0) + hsum4(s1)) + (hsum4(s2) + hsum4(s3));
        }
        __syncthreads();
        {                                       // GW[c], c = tid : 64 f4 loads
            const float4* Wr = reinterpret_cast<const float4*>(Wz + (size_t)tid * 256);
            const float4* G4 = reinterpret_cast<const float4*>(gl);
            float4 s0 = {0,0,0,0}, s1 = {0,0,0,0}, s2 = {0,0,0,0}, s3 = {0,0,0,0};
            #pragma unroll 4
            for (int k = 0; k < 64; k += 4) {
                fma4v(s0, Wr[k], G4[k]);         fma4v(s1, Wr[k + 1], G4[k + 1]);
                fma4v(s2, Wr[k + 2], G4[k + 2]); fma4v(s3, Wr[k + 3], G4[k + 3]);
            }
            GW[((size_t)n * 8 + t) * 512 + tid] =
                (hsum4(s0) + hsum4(s1)) + (hsum4(s2) + hsum4(s3));
        }
        return;
    }
    // ---- fsmall for block b ----
    int n = b >> 6; int s0i = (b & 63) << 7;
    int lane = tid & 63; int wv = tid >> 6;
    {
        const float4* src = reinterpret_cast<const float4*>(M + n * 4096);
        float4* dst = reinterpret_cast<float4*>(&Ml[0][0]);
        for (int i = tid; i < 1024; i += 512) dst[i] = src[i];
    }
    __syncthreads();
    const float* xb = x + (size_t)n * 4194304 + s0i + lane * 2;
    float2 p2[8];
    #pragma unroll
    for (int k = 0; k < 8; ++k) p2[k] = make_float2(0.f, 0.f);
    #pragma unroll 16
    for (int j = 0; j < 64; ++j) {
        int c = wv * 64 + j;
        float2 xv = *reinterpret_cast<const float2*>(xb + (size_t)c * 8192);
        float4 m0 = *reinterpret_cast<const float4*>(&Ml[c][0]);
        float4 m1 = *reinterpret_cast<const float4*>(&Ml[c][4]);
        p2[0].x = fmaf(xv.x, m0.x, p2[0].x); p2[0].y = fmaf(xv.y, m0.x, p2[0].y);
        p2[1].x = fmaf(xv.x, m0.y, p2[1].x); p2[1].y = fmaf(xv.y, m0.y, p2[1].y);
        p2[2].x = fmaf(xv.x, m0.z, p2[2].x); p2[2].y = fmaf(xv.y, m0.z, p2[2].y);
        p2[3].x = fmaf(xv.x, m0.w, p2[3].x); p2[3].y = fmaf(xv.y, m0.w, p2[3].y);
        p2[4].x = fmaf(xv.x, m1.x, p2[4].x); p2[4].y = fmaf(xv.y, m1.x, p2[4].y);
        p2[5].x = fmaf(xv.x, m1.y, p2[5].x); p2[5].y = fmaf(xv.y, m1.y, p2[5].y);
        p2[6].x = fmaf(xv.x, m1.z, p2[6].x); p2[6].y = fmaf(xv.y, m1.z, p2[6].y);
        p2[7].x = fmaf(xv.x, m1.w, p2[7].x); p2[7].y = fmaf(xv.y, m1.w, p2[7].y);
    }
    #pragma unroll
    for (int k = 0; k < 8; ++k)
        *reinterpret_cast<float2*>(&ldsT[wv][k][lane * 2]) = p2[k];
    __syncthreads();
    if (tid < 128) {
        int tok = tid; int wq = tid >> 6;
        const float* ct = constT + n * 8;
        float q[8];
        #pragma unroll
        for (int k = 0; k < 8; ++k) {
            float v = ct[k];
            #pragma unroll
            for (int g = 0; g < 8; ++g) v += ldsT[g][k][tok];
            q[k] = v;
        }
        float4* op = reinterpret_cast<float4*>(fs + ((size_t)n * 8192 + s0i + tok) * 8);
        op[0] = make_float4(q[0], q[1], q[2], q[3]);
        op[1] = make_float4(q[4], q[5], q[6], q[7]);
        float mom[44];
        {
            int idx = 8;
            for (int t1 = 0; t1 < 8; ++t1) {
                mom[t1] = q[t1];
                for (int t2 = t1; t2 < 8; ++t2) { mom[idx] = q[t1] * q[t2]; ++idx; }
            }
        }
        for (int k = 0; k < 44; ++k)
            for (int off = 32; off > 0; off >>= 1) mom[k] += __shfl_down(mom[k], off);
        if ((tid & 63) == 0)
            for (int k = 0; k < 44; ++k) partm[wq][k] = mom[k];
    }
    __syncthreads();
    if (tid < 44) Part[b * 44 + tid] = partm[0][tid] + partm[1][tid];
}

// ---------------- BN fold (redundant per block) + W_y + blend + LayerNorm ----------------
__global__ __launch_bounds__(512, 4) void k_final(
    const float* __restrict__ x, const float* __restrict__ fs,
    const float* __restrict__ Part, const float* __restrict__ GW,
    const float* __restrict__ bz, const float* __restrict__ bng, const float* __restrict__ bnb,
    const float* __restrict__ lng, const float* __restrict__ lnb,
    float* __restrict__ outZ)
{
    int b = blockIdx.x; int n = b >> 6; int s0 = (b & 63) << 7;
    int tid = threadIdx.x; int lane = tid & 63; int wv = tid >> 6;
    __shared__ float GWl[512][8];
    __shared__ float4 PKl[512];
    __shared__ float redS[2][8][130];
    __shared__ float Fl[64];
    __shared__ float S2l[512];
    if (tid < 352) {                            // fold Part: 8 n x 44 moments
        int n2 = tid / 44, k = tid % 44;
        float v = 0.f;
        for (int i = 0; i < 64; ++i) v += Part[(n2 * 64 + i) * 44 + k];
        if (k < 8) Fl[n2 * 8 + k] = v;
        else {
            int kk = k - 8; int t1 = 0;
            while (kk >= 8 - t1) { kk -= 8 - t1; ++t1; }
            int t2 = t1 + kk;
            S2l[n2 * 64 + t1 * 8 + t2] = v;
            S2l[n2 * 64 + t2 * 8 + t1] = v;
        }
    }
    __syncthreads();
    {
        int c = tid;
        const float r = 1.f / 8192.f;
        float meanu = 0.f, e2 = 0.f;
        float gmine[8];
        for (int n2 = 0; n2 < 8; ++n2) {
            float g[8];
            #pragma unroll
            for (int t = 0; t < 8; ++t) g[t] = GW[(n2 * 8 + t) * 512 + c];
            if (n2 == n) {
                #pragma unroll
                for (int t = 0; t < 8; ++t) gmine[t] = g[t];
            }
            #pragma unroll
            for (int t = 0; t < 8; ++t) meanu += Fl[n2 * 8 + t] * g[t];
            for (int t1 = 0; t1 < 8; ++t1)
                #pragma unroll
                for (int t2 = 0; t2 < 8; ++t2) e2 += S2l[n2 * 64 + t1 * 8 + t2] * g[t1] * g[t2];
        }
        const float invCnt = 1.f / 65536.f;
        meanu *= r * invCnt;
        e2 *= r * r * invCnt;
        float var = fmaxf(e2 - meanu * meanu, 0.f);
        float bzv = bz[c];
        float sc = bng[c] * rsqrtf(var + 1e-5f);
        float sh = bnb[c] - (meanu + bzv) * sc;
        float4 pk;
        pk.x = 0.5f * (bzv * sc + sh);
        pk.y = lng[c];
        pk.z = lnb[c];
        pk.w = 0.f;
        PKl[c] = pk;
        float scale = 0.5f * r * sc;
        #pragma unroll
        for (int t = 0; t < 8; ++t) GWl[c][t] = gmine[t] * scale;
    }
    __syncthreads();
    float4 fA0, fB0, fA1, fB1;
    {
        const float4* fp = reinterpret_cast<const float4*>(fs + ((size_t)n * 8192 + s0 + lane * 2) * 8);
        fA0 = fp[0]; fB0 = fp[1]; fA1 = fp[2]; fB1 = fp[3];
    }
    const size_t xbase = (size_t)n * 4194304 + s0 + lane * 2;
    float2 s1 = make_float2(0.f, 0.f), sq = make_float2(0.f, 0.f);
    #pragma unroll 16
    for (int j = 0; j < 64; ++j) {
        int c = wv * 64 + j;
        float2 xv = *reinterpret_cast<const float2*>(&x[xbase + (size_t)c * 8192]);
        float4 g0 = *reinterpret_cast<const float4*>(&GWl[c][0]);
        float4 g1 = *reinterpret_cast<const float4*>(&GWl[c][4]);
        float pk0 = PKl[c].x;
        float z0 = pk0 + 0.5f * xv.x
            + fA0.x * g0.x + fA0.y * g0.y + fA0.z * g0.z + fA0.w * g0.w
            + fB0.x * g1.x + fB0.y * g1.y + fB0.z * g1.z + fB0.w * g1.w;
        float z1 = pk0 + 0.5f * xv.y
            + fA1.x * g0.x + fA1.y * g0.y + fA1.z * g0.z + fA1.w * g0.w
            + fB1.x * g1.x + fB1.y * g1.y + fB1.z * g1.z + fB1.w * g1.w;
        s1.x += z0; sq.x += z0 * z0;
        s1.y += z1; sq.y += z1 * z1;
    }
    *reinterpret_cast<float2*>(&redS[0][wv][lane * 2]) = s1;
    *reinterpret_cast<float2*>(&redS[1][wv][lane * 2]) = sq;
    __syncthreads();
    float mean0, rstd0, mean1, rstd1;
    {
        int t0 = lane * 2, t1 = lane * 2 + 1;
        float a0 = 0.f, q0 = 0.f, a1 = 0.f, q1 = 0.f;
        #pragma unroll
        for (int g = 0; g < 8; ++g) {
            a0 += redS[0][g][t0]; q0 += redS[1][g][t0];
            a1 += redS[0][g][t1]; q1 += redS[1][g][t1];
        }
        mean0 = a0 * (1.f / 512.f);
        rstd0 = rsqrtf(fmaxf(q0 * (1.f / 512.f) - mean0 * mean0, 0.f) + 1e-5f);
        mean1 = a1 * (1.f / 512.f);
        rstd1 = rsqrtf(fmaxf(q1 * (1.f / 512.f) - mean1 * mean1, 0.f) + 1e-5f);
    }
    #pragma unroll 16
    for (int j = 0; j < 64; ++j) {
        int c = wv * 64 + j;
        float2 xv = *reinterpret_cast<const float2*>(&x[xbase + (size_t)c * 8192]);
        float4 g0 = *reinterpret_cast<const float4*>(&GWl[c][0]);
        float4 g1 = *reinterpret_cast<const float4*>(&GWl[c][4]);
        float4 pk = PKl[c];
        float z0 = pk.x + 0.5f * xv.x
            + fA0.x * g0.x + fA0.y * g0.y + fA0.z * g0.z + fA0.w * g0.w
            + fB0.x * g1.x + fB0.y * g1.y + fB0.z * g1.z + fB0.w * g1.w;
        float z1 = pk.x + 0.5f * xv.y
            + fA1.x * g0.x + fA1.y * g0.y + fA1.z * g0.z + fA1.w * g0.w
            + fB1.x * g1.x + fB1.y * g1.y + fB1.z * g1.z + fB1.w * g1.w;
        f32x2 o;
        o.x = (z0 - mean0) * rstd0 * pk.y + pk.z;
        o.y = (z1 - mean1) * rstd1 * pk.y + pk.z;
        __builtin_nontemporal_store(o, reinterpret_cast<f32x2*>(&outZ[xbase + (size_t)c * 8192]));
    }
}

extern "C" void kernel_launch(void* const* d_in, const int* in_sizes, int n_in,
                              void* d_out, int out_size, void* d_ws, size_t ws_size,
                              hipStream_t stream)
{
    const float* x      = (const float*)d_in[0];
    const float* audio  = (const float*)d_in[1];
    const float* alignW = (const float*)d_in[2];
    const float* alignB = (const float*)d_in[3];
    const float* Wg     = (const float*)d_in[4];
    const float* bg     = (const float*)d_in[5];
    const float* Wth    = (const float*)d_in[6];
    const float* bth    = (const float*)d_in[7];
    const float* Wph    = (const float*)d_in[8];
    const float* bph    = (const float*)d_in[9];
    const float* Wz     = (const float*)d_in[10];
    const float* bz     = (const float*)d_in[11];
    const float* bng    = (const float*)d_in[12];
    const float* bnb    = (const float*)d_in[13];
    const float* lng    = (const float*)d_in[14];
    const float* lnb    = (const float*)d_in[15];
    float* outZ = (float*)d_out;
    float* outA = outZ + 33554432;  // z (N,C,T,H,W) then audio_temp (N,T,C)

    uintptr_t pa = ((uintptr_t)d_ws + 255) & ~(uintptr_t)255;
    float* w = (float*)pa;

    float* constT = w;              // 64
    float* M      = w + 64;         // 32768  [n][c][t]
    float* XS     = w + 32832;      // 32768  transposed [n][t][c]
    float* GW     = w + 65600;      // 32768  [n][t][c]
    float* Part   = w + 98368;      // 22528  [512 blocks][44] moment partials
    float* fsm    = w + 120896;     // 524288 [n][s][t]
    // every buffer fully written before read each call -> no memset needed

    k_stage1<<<8256, 256, 0, stream>>>(x, audio, alignW, alignB, Wph, bph, Wth, bth,
                                       outA, constT, M, XS);
    k_stage2<<<576, 512, 0, stream>>>(x, M, constT, XS, Wg, bg, Wz, fsm, Part, GW);
    k_final<<<512, 512, 0, stream>>>(x, fsm, Part, GW, bz, bng, bnb, lng, lnb, outZ);
}